// Round 2
// baseline (353.009 us; speedup 1.0000x reference)
//
#include <hip/hip_runtime.h>
#include <math.h>

#define NN 512
#define NC 3

// Radial cutoff envelope e[i][j] = (r<4.5)/r, r=sqrt((i+1)^2+(j+1)^2), i,j in 0..3
__device__ __constant__ float d_env[16] = {
    0.70710678f, 0.44721360f, 0.31622777f, 0.24253563f,
    0.44721360f, 0.35355339f, 0.27735010f, 0.22360680f,
    0.31622777f, 0.27735010f, 0.23570226f, 0.00000000f,
    0.24253563f, 0.22360680f, 0.00000000f, 0.00000000f
};

// p-major sine table: ws[p*4 + j] = sin(pi * p * (j+1) / 511), p in 0..511.
// One float4 load at ws + 4*p yields all 4 harmonics for coordinate p.
__global__ __launch_bounds__(256) void sine_table_kernel(float* __restrict__ ws) {
    const int t = blockIdx.x * 256 + threadIdx.x;   // 2048 threads
    const int j = t & 3;
    const int p = t >> 2;
    ws[t] = sinf((float)M_PI * (float)p * (1.0f / 511.0f) * (float)(j + 1));
}

// One block = one (b, row-pair): rows y0, y0+1 of batch b. 256 threads:
// threads [0,128) -> row y0, threads [128,256) -> row y0+1; each thread owns
// 4 pixels x = (tid&127) + k*128. Adjacent lanes keep adjacent pixels (the
// round-1 win: each gather instruction spans ~4-5 cache lines), while
// 4 px/thread doubles the independent-gather ILP (48 loads in flight) and
// halves per-pixel setup cost (cu/cv fold, sy load).
__global__ __launch_bounds__(256) void diffeo_kernel(
    const float* __restrict__ xin,
    const float* __restrict__ Fx,
    const float* __restrict__ Fy,
    float* __restrict__ out,
    const float* __restrict__ ws,
    float scale)
{
    const int tid = threadIdx.x;
    const int bid = blockIdx.x;
    // XCD-contiguous assignment: 16384 blocks, 8 XCDs, bijective (16384%8==0).
    // XCD k gets row-pairs [k*2048, (k+1)*2048) = 8 consecutive batches ->
    // vertically-overlapping gather bands stay in one XCD's L2.
    const int rp = ((bid & 7) << 11) | (bid >> 3);
    const int b  = rp >> 8;                         // wave-uniform
    const int y  = ((rp & 255) << 1) | (tid >> 7);  // wave-uniform (half per 2 waves)
    const int xb = tid & 127;

    // per-row sine vector sy[j] (one float4 load)
    const float4 sy = *(const float4*)(ws + y * 4);
    const float syv[4] = { sy.x, sy.y, sy.z, sy.w };

    // fold F*e*sy over j, scale included: cu[i] = scale * sum_j F[b,i,j]*e[i,j]*sy[j]
    const float* fx = Fx + b * 16;
    const float* fy = Fy + b * 16;
    float cu[4], cv[4];
#pragma unroll
    for (int i = 0; i < 4; ++i) {
        float su = 0.0f, sv = 0.0f;
#pragma unroll
        for (int j = 0; j < 4; ++j) {
            const float w = d_env[i * 4 + j] * syv[j];
            su += fx[i * 4 + j] * w;
            sv += fy[i * 4 + j] * w;
        }
        cu[i] = scale * su;
        cv[i] = scale * sv;
    }

    const float* __restrict__ base  = xin + (size_t)b * NC * NN * NN;
    float* __restrict__       obase = out + (size_t)b * NC * NN * NN + (size_t)y * NN;
    const float yr = (float)y;

#pragma unroll
    for (int k = 0; k < 4; ++k) {
        const int xx = xb + (k << 7);

        // sx[i] for this pixel: one float4 load from the p-major table
        const float4 sx = *(const float4*)(ws + xx * 4);
        const float du = sx.x * cu[0] + sx.y * cu[1] + sx.z * cu[2] + sx.w * cu[3];
        const float dv = sx.x * cv[0] + sx.y * cv[1] + sx.z * cv[2] + sx.w * cv[3];

        const float xn = fminf(fmaxf((float)xx - du, 0.0f), 511.0f);
        const float yn = fminf(fmaxf(yr - dv, 0.0f), 511.0f);
        const float xff = floorf(xn), yff = floorf(yn);
        const int xf = (int)xff, yf = (int)yff;
        const int xc = min(xf + 1, NN - 1);   // == ceil for non-integer xn; weight 0 otherwise
        const int yc = min(yf + 1, NN - 1);
        const float xv = xn - xff, yv = yn - yff;

        const int o00 = yf * NN + xf;
        const int o01 = yf * NN + xc;
        const int o10 = yc * NN + xf;
        const int o11 = yc * NN + xc;

#pragma unroll
        for (int c = 0; c < NC; ++c) {
            const float* img = base + c * NN * NN;
            const float v00 = img[o00];
            const float v01 = img[o01];
            const float v10 = img[o10];
            const float v11 = img[o11];
            const float top = v00 + xv * (v01 - v00);
            const float bot = v10 + xv * (v11 - v10);
            // nontemporal: output is never re-read; keep it from evicting the
            // input image out of L2/L3 (should lower FETCH_SIZE).
            __builtin_nontemporal_store(top + yv * (bot - top),
                                        obase + c * NN * NN + xx);
        }
    }
}

extern "C" void kernel_launch(void* const* d_in, const int* in_sizes, int n_in,
                              void* d_out, int out_size, void* d_ws, size_t ws_size,
                              hipStream_t stream) {
    const float* x  = (const float*)d_in[0];
    const float* Fx = (const float*)d_in[1];
    const float* Fy = (const float*)d_in[2];
    float* out = (float*)d_out;
    float* ws  = (float*)d_ws;   // 8 KB sine table (re-built every call; ws re-poisoned)

    // typ = n * sqrt(pi*log(cut)) / 2 ; scale = sqrt(T/typ^2) * n
    const double typ = 512.0 * sqrt(M_PI * log(4.0)) / 2.0;
    const float scale = (float)(sqrt(0.01 / (typ * typ)) * 512.0);

    sine_table_kernel<<<8, 256, 0, stream>>>(ws);
    diffeo_kernel<<<64 * 512 / 2, 256, 0, stream>>>(x, Fx, Fy, out, ws, scale);
}

// Round 3
// 337.448 us; speedup vs baseline: 1.0461x; 1.0461x over previous
//
#include <hip/hip_runtime.h>
#include <math.h>

#define NN 512
#define NC 3

// Radial cutoff envelope e[i][j] = (r<4.5)/r, r=sqrt((i+1)^2+(j+1)^2), i,j in 0..3
__device__ __constant__ float d_env[16] = {
    0.70710678f, 0.44721360f, 0.31622777f, 0.24253563f,
    0.44721360f, 0.35355339f, 0.27735010f, 0.22360680f,
    0.31622777f, 0.27735010f, 0.23570226f, 0.00000000f,
    0.24253563f, 0.22360680f, 0.00000000f, 0.00000000f
};

// p-major sine table: ws[p*4 + j] = sin(pi * p * (j+1) / 511), p in 0..511.
// Serves both axes (n == m == 512): sx = ws4[x], sy = ws4[y].
__global__ __launch_bounds__(256) void sine_table_kernel(float* __restrict__ ws) {
    const int t = blockIdx.x * 256 + threadIdx.x;   // 2048 threads
    const int j = t & 3;
    const int p = t >> 2;
    ws[t] = sinf((float)M_PI * (float)p * (1.0f / 511.0f) * (float)(j + 1));
}

// Async global->LDS, 16 B per lane (dest must be linear: base + lane*16).
#define GLOAD_LDS(g, l)                                                        \
    __builtin_amdgcn_global_load_lds(                                          \
        (const __attribute__((address_space(1))) void*)(g),                    \
        (__attribute__((address_space(3))) void*)(l), 16, 0, 0)

// One block = one (b, 8-row group). The displacement field is sub-pixel-to-
// ~1.5px (scale ~= 0.096), so bilinear taps form a tight stencil: stage a
// 12-row x 512 x 3ch band (+2-row halo each side) in LDS and do the 12 taps
// per pixel as ds_read2_b32 pairs. This moves ~200M gather lane-addresses off
// the TA/L1 pipe (the round-2 bottleneck: ~4 addr/cyc/CU ~= 110 us) onto the
// DS pipe (~20 us). A per-pixel in-band test with full global-gather fallback
// keeps it correct for arbitrarily large displacements.
// LDS = 3*12*512 + 2048 floats = 81920 B exactly -> 2 blocks/CU, so one
// block's staging overlaps the other's compute.
__global__ __launch_bounds__(512, 4) void diffeo_kernel(
    const float* __restrict__ xin,
    const float* __restrict__ Fx,
    const float* __restrict__ Fy,
    float* __restrict__ out,
    const float* __restrict__ ws,
    float scale)
{
    const int tid = threadIdx.x;
    const int bid = blockIdx.x;
    // XCD-contiguous assignment: 4096 blocks, 8 XCDs, bijective (4096%8==0).
    // Consecutive row-groups (shared halo rows) stay on one XCD's L2.
    const int g  = ((bid & 7) << 9) | (bid >> 3);
    const int b  = g >> 6;                 // wave-uniform
    const int y0 = (g & 63) << 3;          // first output row of this block
    const int lo = y0 - 2;                 // first staged row (may be <0, clamped)

    __shared__ float smem[20480];          // [3][12][512] tile + [512] float4 ws
    const float* __restrict__ base = xin + (size_t)b * NC * NN * NN;

    // ---- stage sine table: 512 float4 by 512 threads ----
    GLOAD_LDS(ws + (tid << 2), smem + 18432 + (tid << 2));

    // ---- stage 12-row x 3-ch band: 4608 float4, 9 per thread ----
#pragma unroll
    for (int k = 0; k < 9; ++k) {
        const int f   = tid + (k << 9);              // float4 index in tile
        const int ch  = (f >= 3072) ? 2 : ((f >= 1536) ? 1 : 0);
        const int rem = f - ch * 1536;
        const int srow = rem >> 7;                   // staged slot 0..11
        const int seg  = rem & 127;                  // float4 within row
        const int row  = min(max(lo + srow, 0), NN - 1);
        GLOAD_LDS(base + ((ch << 18) | (row << 9) | (seg << 2)),
                  smem + (f << 2));
    }

    // ---- per-row coefficient fold (amortized over 8 px/thread) ----
    const int y  = y0 + (tid >> 6);                  // wave-uniform row
    const int xb = tid & 63;

    const float* fx = Fx + b * 16;
    const float* fy = Fy + b * 16;

    __syncthreads();                                 // drains vmcnt + barrier

    const float4 sy = *(const float4*)(smem + 18432 + (y << 2));  // broadcast
    const float syv[4] = { sy.x, sy.y, sy.z, sy.w };

    float cu[4], cv[4];
#pragma unroll
    for (int i = 0; i < 4; ++i) {
        float su = 0.0f, sv = 0.0f;
#pragma unroll
        for (int j = 0; j < 4; ++j) {
            const float w = d_env[i * 4 + j] * syv[j];
            su += fx[i * 4 + j] * w;
            sv += fy[i * 4 + j] * w;
        }
        cu[i] = scale * su;
        cv[i] = scale * sv;
    }

    float* __restrict__ obase = out + (size_t)b * NC * NN * NN + (size_t)y * NN;
    const float yr = (float)y;

#pragma unroll 4
    for (int k = 0; k < 8; ++k) {
        const int xx = xb | (k << 6);

        const float4 sx = *(const float4*)(smem + 18432 + (xx << 2));
        const float du = sx.x * cu[0] + sx.y * cu[1] + sx.z * cu[2] + sx.w * cu[3];
        const float dv = sx.x * cv[0] + sx.y * cv[1] + sx.z * cv[2] + sx.w * cv[3];

        const float xn = fminf(fmaxf((float)xx - du, 0.0f), 511.0f);
        const float yn = fminf(fmaxf(yr - dv, 0.0f), 511.0f);
        const float xff = floorf(xn), yff = floorf(yn);
        const int xf = (int)xff, yf = (int)yff;
        const float xv = xn - xff, yv = yn - yff;

        float o0, o1, o2;
        // In-band: row yf and yf+1 both staged. (yf==lo+11 falls back even
        // when yv==0 — rare and harmless.)
        if (yf >= lo && yf <= lo + 10) {
            // t0[1]/t1[1] may over-read by one element at xf==511 (xv==0,
            // weight exactly 0, value finite) — stays inside smem[20480].
            const float* t0 = smem + (((yf - lo) << 9) + xf);
            const float* t1 = t0 + 512;
#pragma unroll
            for (int c = 0; c < NC; ++c) {
                const float v00 = t0[c * 6144 + 0];
                const float v01 = t0[c * 6144 + 1];
                const float v10 = t1[c * 6144 + 0];
                const float v11 = t1[c * 6144 + 1];
                const float top = v00 + xv * (v01 - v00);
                const float bot = v10 + xv * (v11 - v10);
                const float r = top + yv * (bot - top);
                if (c == 0) o0 = r; else if (c == 1) o1 = r; else o2 = r;
            }
        } else {
            // Rare large-displacement fallback: global bilinear gather.
            const int xc = min(xf + 1, NN - 1);
            const int yc = min(yf + 1, NN - 1);
            const int o00 = yf * NN + xf;
            const int o01 = yf * NN + xc;
            const int o10 = yc * NN + xf;
            const int o11 = yc * NN + xc;
#pragma unroll
            for (int c = 0; c < NC; ++c) {
                const float* img = base + c * NN * NN;
                const float v00 = img[o00];
                const float v01 = img[o01];
                const float v10 = img[o10];
                const float v11 = img[o11];
                const float top = v00 + xv * (v01 - v00);
                const float bot = v10 + xv * (v11 - v10);
                const float r = top + yv * (bot - top);
                if (c == 0) o0 = r; else if (c == 1) o1 = r; else o2 = r;
            }
        }

        // nontemporal: output never re-read; don't evict the input from L2/L3.
        __builtin_nontemporal_store(o0, obase + 0 * NN * NN + xx);
        __builtin_nontemporal_store(o1, obase + 1 * NN * NN + xx);
        __builtin_nontemporal_store(o2, obase + 2 * NN * NN + xx);
    }
}

extern "C" void kernel_launch(void* const* d_in, const int* in_sizes, int n_in,
                              void* d_out, int out_size, void* d_ws, size_t ws_size,
                              hipStream_t stream) {
    const float* x  = (const float*)d_in[0];
    const float* Fx = (const float*)d_in[1];
    const float* Fy = (const float*)d_in[2];
    float* out = (float*)d_out;
    float* ws  = (float*)d_ws;   // 8 KB sine table (re-built every call; ws re-poisoned)

    // typ = n * sqrt(pi*log(cut)) / 2 ; scale = sqrt(T/typ^2) * n
    const double typ = 512.0 * sqrt(M_PI * log(4.0)) / 2.0;
    const float scale = (float)(sqrt(0.01 / (typ * typ)) * 512.0);

    sine_table_kernel<<<8, 256, 0, stream>>>(ws);
    diffeo_kernel<<<64 * 64, 512, 0, stream>>>(x, Fx, Fy, out, ws, scale);
}